// Round 1
// baseline (113.682 us; speedup 1.0000x reference)
//
#include <hip/hip_runtime.h>

// Problem constants (fixed by setup_inputs / reference)
#define FH 2160
#define FW 3840
#define DH 1080
#define DW 1920
#define RAD 8
#define KS 17
#define INV_KS (1.0f / 17.0f)
#define EPS_GF 1e-3f
#define EPS_LOG 1e-6f
#define EPS_SCALE 1e-4f
#define A_COEF 0.7f

__device__ __forceinline__ int refl(int p, int n) {
    // jnp.pad 'reflect' (no edge repeat): -1 -> 1, n -> n-2. RAD < n so one fold suffices.
    p = (p < 0) ? -p : p;
    return (p >= n) ? (2 * n - 2 - p) : p;
}

__device__ __forceinline__ float luma(float r, float g, float b) {
    return 0.2126f * r + 0.7152f * g + 0.0722f * b;
}

// ---- 1. full-res luma -> log2 -> 2x2 average downsample ----
// Exact match to reference: DOWN=0.5 align_corners=False bilinear has wy=wx=0.5
// everywhere -> plain 2x2 mean of Y_log.
__global__ void k_down(const float* __restrict__ x, float* __restrict__ D) {
    int j = blockIdx.x * blockDim.x + threadIdx.x;
    int i = blockIdx.y;
    if (j >= DW) return;
    size_t base0 = ((size_t)(2 * i) * FW + (size_t)(2 * j)) * 3;
    float s = 0.f;
#pragma unroll
    for (int p = 0; p < 2; ++p) {
        const float* r = x + base0 + (size_t)p * FW * 3;
#pragma unroll
        for (int q = 0; q < 2; ++q) {
            float cr = r[q * 3 + 0], cg = r[q * 3 + 1], cb = r[q * 3 + 2];
            float Y = luma(cr, cg, cb);
            s += __log2f(fmaxf(Y, EPS_LOG));
        }
    }
    D[(size_t)i * DW + j] = 0.25f * s;
}

// ---- 2. horizontal box of D and D^2 (reflect pad) ----
__global__ void k_hbox_sq(const float* __restrict__ src,
                          float* __restrict__ h1, float* __restrict__ h2) {
    __shared__ float lds[256 + 2 * RAD];
    int i = blockIdx.y;
    int j0 = blockIdx.x * 256;
    int t = threadIdx.x;
    const float* row = src + (size_t)i * DW;
    lds[t] = row[refl(j0 - RAD + t, DW)];
    if (t < 2 * RAD) lds[256 + t] = row[refl(j0 - RAD + 256 + t, DW)];
    __syncthreads();
    int j = j0 + t;
    if (j < DW) {
        float s1 = 0.f, s2 = 0.f;
#pragma unroll
        for (int k = 0; k < KS; ++k) { float v = lds[t + k]; s1 += v; s2 += v * v; }
        h1[(size_t)i * DW + j] = s1 * INV_KS;
        h2[(size_t)i * DW + j] = s2 * INV_KS;
    }
}

// ---- 3. vertical box of hI,hII -> a,b ----
__global__ void k_vbox1(const float* __restrict__ hI, const float* __restrict__ hII,
                        float* __restrict__ a, float* __restrict__ b) {
    int j = blockIdx.x * blockDim.x + threadIdx.x;
    int i = blockIdx.y;
    if (j >= DW) return;
    float s1 = 0.f, s2 = 0.f;
#pragma unroll
    for (int k = -RAD; k <= RAD; ++k) {
        int r = refl(i + k, DH);
        s1 += hI[(size_t)r * DW + j];
        s2 += hII[(size_t)r * DW + j];
    }
    float mI = s1 * INV_KS, mII = s2 * INV_KS;
    float var = mII - mI * mI;
    float av = var / (var + EPS_GF);
    a[(size_t)i * DW + j] = av;
    b[(size_t)i * DW + j] = mI - av * mI;
}

// ---- 4. horizontal box of a and b ----
__global__ void k_hbox2(const float* __restrict__ A, const float* __restrict__ B,
                        float* __restrict__ hA, float* __restrict__ hB) {
    __shared__ float la[256 + 2 * RAD];
    __shared__ float lb[256 + 2 * RAD];
    int i = blockIdx.y;
    int j0 = blockIdx.x * 256;
    int t = threadIdx.x;
    const float* rowa = A + (size_t)i * DW;
    const float* rowb = B + (size_t)i * DW;
    int c0 = refl(j0 - RAD + t, DW);
    la[t] = rowa[c0];
    lb[t] = rowb[c0];
    if (t < 2 * RAD) {
        int c1 = refl(j0 - RAD + 256 + t, DW);
        la[256 + t] = rowa[c1];
        lb[256 + t] = rowb[c1];
    }
    __syncthreads();
    int j = j0 + t;
    if (j < DW) {
        float s1 = 0.f, s2 = 0.f;
#pragma unroll
        for (int k = 0; k < KS; ++k) { s1 += la[t + k]; s2 += lb[t + k]; }
        hA[(size_t)i * DW + j] = s1 * INV_KS;
        hB[(size_t)i * DW + j] = s2 * INV_KS;
    }
}

// ---- 5. vertical box of ha,hb -> base = mean_a * D + mean_b ----
__global__ void k_vbox2(const float* __restrict__ ha, const float* __restrict__ hb,
                        const float* __restrict__ D, float* __restrict__ base) {
    int j = blockIdx.x * blockDim.x + threadIdx.x;
    int i = blockIdx.y;
    if (j >= DW) return;
    float s1 = 0.f, s2 = 0.f;
#pragma unroll
    for (int k = -RAD; k <= RAD; ++k) {
        int r = refl(i + k, DH);
        s1 += ha[(size_t)r * DW + j];
        s2 += hb[(size_t)r * DW + j];
    }
    float mA = s1 * INV_KS, mB = s2 * INV_KS;
    base[(size_t)i * DW + j] = mA * D[(size_t)i * DW + j] + mB;
}

// ---- 6. upsample base + tone map + scale + clip ----
__global__ void k_final(const float* __restrict__ x, const float* __restrict__ base,
                        float* __restrict__ out) {
    int i = blockIdx.y;
    int jq = blockIdx.x * blockDim.x + threadIdx.x;  // quad of 4 pixels
    if (jq >= FW / 4) return;

    float ys = (i + 0.5f) * 0.5f - 0.5f;
    ys = fminf(fmaxf(ys, 0.f), (float)(DH - 1));
    int y0 = (int)ys;
    int y1 = min(y0 + 1, DH - 1);
    float wy = ys - (float)y0;
    const float* brow0 = base + (size_t)y0 * DW;
    const float* brow1 = base + (size_t)y1 * DW;

    size_t off = ((size_t)i * FW + (size_t)jq * 4) * 3;
    const float4* xin = (const float4*)(x + off);
    float4 v0 = xin[0], v1 = xin[1], v2 = xin[2];
    float px[12] = {v0.x, v0.y, v0.z, v0.w, v1.x, v1.y, v1.z, v1.w,
                    v2.x, v2.y, v2.z, v2.w};
    float po[12];
#pragma unroll
    for (int p = 0; p < 4; ++p) {
        int j = jq * 4 + p;
        float xs = (j + 0.5f) * 0.5f - 0.5f;
        xs = fminf(fmaxf(xs, 0.f), (float)(DW - 1));
        int x0 = (int)xs;
        int x1 = min(x0 + 1, DW - 1);
        float wx = xs - (float)x0;
        float t0 = brow0[x0], t1 = brow0[x1];
        float q0 = brow1[x0], q1 = brow1[x1];
        float top = t0 * (1.f - wx) + t1 * wx;
        float bot = q0 * (1.f - wx) + q1 * wx;
        float Yb = top * (1.f - wy) + bot * wy;

        float cr = px[p * 3 + 0], cg = px[p * 3 + 1], cb = px[p * 3 + 2];
        float Y = luma(cr, cg, cb);
        float Ylog = __log2f(fmaxf(Y, EPS_LOG));
        float Ytm = A_COEF * Yb + (Ylog - Yb);
        float Yout = exp2f(Ytm);
        float scale = Yout / (Y + EPS_SCALE);
        po[p * 3 + 0] = fminf(fmaxf(cr * scale, 0.f), 1.f);
        po[p * 3 + 1] = fminf(fmaxf(cg * scale, 0.f), 1.f);
        po[p * 3 + 2] = fminf(fmaxf(cb * scale, 0.f), 1.f);
    }
    float4* op = (float4*)(out + off);
    op[0] = make_float4(po[0], po[1], po[2], po[3]);
    op[1] = make_float4(po[4], po[5], po[6], po[7]);
    op[2] = make_float4(po[8], po[9], po[10], po[11]);
}

extern "C" void kernel_launch(void* const* d_in, const int* in_sizes, int n_in,
                              void* d_out, int out_size, void* d_ws, size_t ws_size,
                              hipStream_t stream) {
    const float* x = (const float*)d_in[0];
    float* out = (float*)d_out;
    float* ws = (float*)d_ws;
    const size_t DN = (size_t)DW * DH;  // 2,073,600 elems = 8.29 MB each

    // Buffer plan (5 x DN floats = 41.5 MB):
    //   D  : Y_log downsampled (live until k_vbox2)
    //   h1 : hbox(I)  -> reused as hbox(a)
    //   h2 : hbox(II) -> reused as hbox(b)
    //   A  : a        -> reused as base
    //   B  : b
    float* D  = ws;
    float* h1 = ws + DN;
    float* h2 = ws + 2 * DN;
    float* A  = ws + 3 * DN;
    float* B  = ws + 4 * DN;

    dim3 blk(256);
    dim3 grdD((DW + 255) / 256, DH);

    k_down  <<<grdD, blk, 0, stream>>>(x, D);
    k_hbox_sq<<<grdD, blk, 0, stream>>>(D, h1, h2);
    k_vbox1 <<<grdD, blk, 0, stream>>>(h1, h2, A, B);
    k_hbox2 <<<grdD, blk, 0, stream>>>(A, B, h1, h2);
    k_vbox2 <<<grdD, blk, 0, stream>>>(h1, h2, D, /*base=*/A);

    dim3 grdF((FW / 4 + 255) / 256, FH);
    k_final<<<grdF, blk, 0, stream>>>(x, /*base=*/A, out);
}

// Round 2
// 99.561 us; speedup vs baseline: 1.1418x; 1.1418x over previous
//
#include <hip/hip_runtime.h>

// Problem constants (fixed by setup_inputs / reference)
#define FH 2160
#define FW 3840
#define DH 1080
#define DW 1920
#define RAD 8
#define KS 17
#define INV_KS (1.0f / 17.0f)
#define EPS_GF 1e-3f
#define EPS_LOG 1e-6f
#define EPS_SCALE 1e-4f
#define A_COEF 0.7f

// Guided-filter tile geometry
#define TS 32               // output tile
#define IT (TS + 2 * RAD)   // 48: input tile with halo
#define ITP (IT + 1)        // 49: padded LDS stride

__device__ __forceinline__ int refl(int p, int n) {
    // jnp.pad 'reflect' (no edge repeat): -1 -> 1, n -> n-2. RAD < n so one fold suffices.
    p = (p < 0) ? -p : p;
    return (p >= n) ? (2 * n - 2 - p) : p;
}

__device__ __forceinline__ float luma(float r, float g, float b) {
    return 0.2126f * r + 0.7152f * g + 0.0722f * b;
}

// ---- 1. full-res luma -> log2 -> 2x2 average downsample ----
// DOWN=0.5 align_corners=False bilinear == plain 2x2 mean of Y_log.
// Each thread: 2 outputs from 4x2 input pixels = 6 float4 loads, 1 float2 store.
__global__ void k_down(const float* __restrict__ x, float* __restrict__ D) {
    int jp = blockIdx.x * blockDim.x + threadIdx.x;   // pair index, [0, DW/2)
    int i = blockIdx.y;
    if (jp >= DW / 2) return;
    size_t base0 = ((size_t)(2 * i) * FW + (size_t)(4 * jp)) * 3;  // floats; 16B aligned
    const float4* r0 = (const float4*)(x + base0);
    const float4* r1 = (const float4*)(x + base0 + (size_t)FW * 3);
    float4 a0 = r0[0], a1 = r0[1], a2 = r0[2];
    float4 b0 = r1[0], b1 = r1[1], b2 = r1[2];
    float f0[12] = {a0.x, a0.y, a0.z, a0.w, a1.x, a1.y, a1.z, a1.w, a2.x, a2.y, a2.z, a2.w};
    float f1[12] = {b0.x, b0.y, b0.z, b0.w, b1.x, b1.y, b1.z, b1.w, b2.x, b2.y, b2.z, b2.w};
    float yl[2][4];
#pragma unroll
    for (int q = 0; q < 4; ++q) {
        float Y0 = luma(f0[3 * q], f0[3 * q + 1], f0[3 * q + 2]);
        float Y1 = luma(f1[3 * q], f1[3 * q + 1], f1[3 * q + 2]);
        yl[0][q] = __log2f(fmaxf(Y0, EPS_LOG));
        yl[1][q] = __log2f(fmaxf(Y1, EPS_LOG));
    }
    float d0 = 0.25f * (yl[0][0] + yl[0][1] + yl[1][0] + yl[1][1]);
    float d1 = 0.25f * (yl[0][2] + yl[0][3] + yl[1][2] + yl[1][3]);
    float2* dst = (float2*)(D + (size_t)i * DW + 2 * jp);
    *dst = make_float2(d0, d1);
}

// ---- 2. fused GF stage 1: D -> a,b  (hbox+vbox of I and I*I in one block) ----
__global__ void k_gf1(const float* __restrict__ D,
                      float* __restrict__ a, float* __restrict__ b) {
    __shared__ float in[IT * ITP];
    __shared__ float h1[IT * TS];
    __shared__ float h2[IT * TS];
    int tx0 = blockIdx.x * TS, ty0 = blockIdx.y * TS;
    int t = threadIdx.x;

    for (int idx = t; idx < IT * IT; idx += 256) {
        int li = idx / IT, lj = idx - li * IT;
        int gi = refl(ty0 - RAD + li, DH);
        int gj = refl(tx0 - RAD + lj, DW);
        in[li * ITP + lj] = D[(size_t)gi * DW + gj];
    }
    __syncthreads();

    for (int idx = t; idx < IT * TS; idx += 256) {
        int r = idx >> 5, c = idx & (TS - 1);
        const float* row = &in[r * ITP + c];
        float s1 = 0.f, s2 = 0.f;
#pragma unroll
        for (int k = 0; k < KS; ++k) { float v = row[k]; s1 += v; s2 += v * v; }
        h1[idx] = s1 * INV_KS;
        h2[idx] = s2 * INV_KS;
    }
    __syncthreads();

    for (int idx = t; idx < TS * TS; idx += 256) {
        int r = idx >> 5, c = idx & (TS - 1);
        float s1 = 0.f, s2 = 0.f;
#pragma unroll
        for (int k = 0; k < KS; ++k) {
            s1 += h1[(r + k) * TS + c];
            s2 += h2[(r + k) * TS + c];
        }
        int gi = ty0 + r, gj = tx0 + c;
        if (gi < DH) {
            float mI = s1 * INV_KS, mII = s2 * INV_KS;
            float var = mII - mI * mI;
            float av = var / (var + EPS_GF);
            a[(size_t)gi * DW + gj] = av;
            b[(size_t)gi * DW + gj] = mI - av * mI;
        }
    }
}

// ---- 3. fused GF stage 2: a,b,D -> base = mean_a * D + mean_b ----
__global__ void k_gf2(const float* __restrict__ A, const float* __restrict__ B,
                      const float* __restrict__ D, float* __restrict__ base) {
    __shared__ float inA[IT * ITP];
    __shared__ float inB[IT * ITP];
    __shared__ float hA[IT * TS];
    __shared__ float hB[IT * TS];
    int tx0 = blockIdx.x * TS, ty0 = blockIdx.y * TS;
    int t = threadIdx.x;

    for (int idx = t; idx < IT * IT; idx += 256) {
        int li = idx / IT, lj = idx - li * IT;
        int gi = refl(ty0 - RAD + li, DH);
        int gj = refl(tx0 - RAD + lj, DW);
        size_t g = (size_t)gi * DW + gj;
        inA[li * ITP + lj] = A[g];
        inB[li * ITP + lj] = B[g];
    }
    __syncthreads();

    for (int idx = t; idx < IT * TS; idx += 256) {
        int r = idx >> 5, c = idx & (TS - 1);
        const float* rowa = &inA[r * ITP + c];
        const float* rowb = &inB[r * ITP + c];
        float s1 = 0.f, s2 = 0.f;
#pragma unroll
        for (int k = 0; k < KS; ++k) { s1 += rowa[k]; s2 += rowb[k]; }
        hA[idx] = s1 * INV_KS;
        hB[idx] = s2 * INV_KS;
    }
    __syncthreads();

    for (int idx = t; idx < TS * TS; idx += 256) {
        int r = idx >> 5, c = idx & (TS - 1);
        float s1 = 0.f, s2 = 0.f;
#pragma unroll
        for (int k = 0; k < KS; ++k) {
            s1 += hA[(r + k) * TS + c];
            s2 += hB[(r + k) * TS + c];
        }
        int gi = ty0 + r, gj = tx0 + c;
        if (gi < DH) {
            float mA = s1 * INV_KS, mB = s2 * INV_KS;
            size_t g = (size_t)gi * DW + gj;
            base[g] = mA * D[g] + mB;
        }
    }
}

// ---- 4. upsample base + tone map + scale + clip ----
__global__ void k_final(const float* __restrict__ x, const float* __restrict__ base,
                        float* __restrict__ out) {
    int i = blockIdx.y;
    int jq = blockIdx.x * blockDim.x + threadIdx.x;  // quad of 4 pixels
    if (jq >= FW / 4) return;

    float ys = (i + 0.5f) * 0.5f - 0.5f;
    ys = fminf(fmaxf(ys, 0.f), (float)(DH - 1));
    int y0 = (int)ys;
    int y1 = min(y0 + 1, DH - 1);
    float wy = ys - (float)y0;
    const float* brow0 = base + (size_t)y0 * DW;
    const float* brow1 = base + (size_t)y1 * DW;

    size_t off = ((size_t)i * FW + (size_t)jq * 4) * 3;
    const float4* xin = (const float4*)(x + off);
    float4 v0 = xin[0], v1 = xin[1], v2 = xin[2];
    float px[12] = {v0.x, v0.y, v0.z, v0.w, v1.x, v1.y, v1.z, v1.w,
                    v2.x, v2.y, v2.z, v2.w};
    float po[12];
#pragma unroll
    for (int p = 0; p < 4; ++p) {
        int j = jq * 4 + p;
        float xs = (j + 0.5f) * 0.5f - 0.5f;
        xs = fminf(fmaxf(xs, 0.f), (float)(DW - 1));
        int x0 = (int)xs;
        int x1 = min(x0 + 1, DW - 1);
        float wx = xs - (float)x0;
        float t0 = brow0[x0], t1 = brow0[x1];
        float q0 = brow1[x0], q1 = brow1[x1];
        float top = t0 * (1.f - wx) + t1 * wx;
        float bot = q0 * (1.f - wx) + q1 * wx;
        float Yb = top * (1.f - wy) + bot * wy;

        float cr = px[p * 3 + 0], cg = px[p * 3 + 1], cb = px[p * 3 + 2];
        float Y = luma(cr, cg, cb);
        float Ylog = __log2f(fmaxf(Y, EPS_LOG));
        float Ytm = A_COEF * Yb + (Ylog - Yb);
        float Yout = exp2f(Ytm);
        float scale = Yout / (Y + EPS_SCALE);
        po[p * 3 + 0] = fminf(fmaxf(cr * scale, 0.f), 1.f);
        po[p * 3 + 1] = fminf(fmaxf(cg * scale, 0.f), 1.f);
        po[p * 3 + 2] = fminf(fmaxf(cb * scale, 0.f), 1.f);
    }
    float4* op = (float4*)(out + off);
    op[0] = make_float4(po[0], po[1], po[2], po[3]);
    op[1] = make_float4(po[4], po[5], po[6], po[7]);
    op[2] = make_float4(po[8], po[9], po[10], po[11]);
}

extern "C" void kernel_launch(void* const* d_in, const int* in_sizes, int n_in,
                              void* d_out, int out_size, void* d_ws, size_t ws_size,
                              hipStream_t stream) {
    const float* x = (const float*)d_in[0];
    float* out = (float*)d_out;
    float* ws = (float*)d_ws;
    const size_t DN = (size_t)DW * DH;  // 2,073,600 elems = 8.29 MB each

    // Buffer plan (4 x DN floats = 33.2 MB):
    //   D : Y_log downsampled (live until k_gf2)
    //   A : a   -> reused as base by k_gf2? no: base written to A after a consumed
    //   B : b
    float* D = ws;
    float* A = ws + DN;
    float* B = ws + 2 * DN;
    float* BASE = ws + 3 * DN;

    dim3 blk(256);

    dim3 grdDown((DW / 2 + 255) / 256, DH);
    k_down<<<grdDown, blk, 0, stream>>>(x, D);

    dim3 grdGF(DW / TS, (DH + TS - 1) / TS);  // 60 x 34
    k_gf1<<<grdGF, blk, 0, stream>>>(D, A, B);
    k_gf2<<<grdGF, blk, 0, stream>>>(A, B, D, BASE);

    dim3 grdF((FW / 4 + 255) / 256, FH);
    k_final<<<grdF, blk, 0, stream>>>(x, BASE, out);
}